// Round 4
// baseline (236.305 us; speedup 1.0000x reference)
//
#include <hip/hip_runtime.h>

// LNCC, separable 5-tap Gaussian (sigma=1), fused single pass.
// (N=2, C=1, D=160, H=192, W=224) fp32 -> scalar.
// R9: single-buffered LDS (18.6 KB, was 37.4 KB) via two-phase iteration:
//     Phase A = all LDS reads (H-blur of last iter's wbA; W-blur reads sIJ,
//     results kept in 5 regs) | barrier | Phase B = all LDS writes (commit
//     wbA/wbC, stage prefetched slice) | barrier. Rationale: occupancy
//     counter shows ~1 block/CU resident across R6/R7/R8 (38/20.5/38% =
//     ~1.2 blocks) -> every barrier stall exposed. 18.6 KB fits 3 blocks
//     (30 waves/CU, wave-limited) even under a 64 KB effective budget.
//     Keeps R8's packed-fp32 math (v_pk_fma_f32) and register D-pipeline.

#define NB 2
#define DD 160
#define HH 192
#define WW 224
#define SH 224
#define SD (224*192)
#define SN (224*192*160)

#define TW 32
#define TH 16
#define ROWS (TH+4)          // 20
#define DCHUNK 20
#define NCHUNK (DD/DCHUNK)   // 8

#define K0 0.05448868f
#define K1 0.24420134f
#define K2 0.40261995f

typedef float v2f __attribute__((ext_vector_type(2)));
typedef float v4f __attribute__((ext_vector_type(4)));

__global__ __launch_bounds__(640) void lncc_main(
    const float* __restrict__ A, const float* __restrict__ B,
    const float* __restrict__ M, double* __restrict__ acc)
{
    __shared__ v2f  sIJ[ROWS][36];   // raw (I,J) + W halo, single buffer
    __shared__ v4f  wbA[ROWS][32];   // (bI,bJ,bII,bJJ), single buffer
    __shared__ float wbC[ROWS][32];  // bIJ, single buffer
    __shared__ float redL[10], redM[10];

    const int wt = blockIdx.x;           // 0..6
    const int ht = blockIdx.y;           // 0..11
    const int zz = blockIdx.z;           // 0..15
    const int n  = zz >> 3;
    const int dc = zz & 7;
    const int w0 = wt * TW, h0 = ht * TH, d0 = dc * DCHUNK;

    const float* __restrict__ Ai = A + (size_t)n * SN;
    const float* __restrict__ Bi = B + (size_t)n * SN;
    const float* __restrict__ Mi = M + (size_t)n * SN;

    const int tid = threadIdx.x;
    const int r   = tid >> 5;            // 0..19
    const int c   = tid & 31;            // 0..31

    const int gh  = h0 + r - 2;
    const bool hv = (unsigned)gh < (unsigned)HH;
    const int ghc = hv ? gh : 0;
    const int hwm = ghc * SH + (w0 + c);          // 32-bit offsets
    const int gwl = w0 + c - 2, gwr = w0 + c + 2;
    const bool lv = hv && (c < 2)   && (gwl >= 0);
    const bool rv = hv && (c >= 30) && (gwr < WW);
    const bool anyh = lv || rv;
    const int hwh = ghc * SH + (lv ? gwl : (rv ? gwr : 0));
    const int mbase = (h0 + r) * SH + (w0 + c);

    // D-direction shift-register pipelines (oldest..newest)
    v2f pP0 = 0.f, pP1 = 0.f, pP2 = 0.f, pP3 = 0.f;   // (bI,bJ)
    v2f pQ0 = 0.f, pQ1 = 0.f, pQ2 = 0.f, pQ3 = 0.f;   // (bII,bJJ)
    float pC0 = 0.f, pC1 = 0.f, pC2 = 0.f, pC3 = 0.f; // bIJ
    float accL = 0.f, accM = 0.f;

    // prefetch registers for the slice staged in phase B of iteration k
    v2f nM = 0.f, nH = 0.f;
    {
        const int dd = d0 - 2;
        if (dd >= 0) {
            const int dof = dd * SD;
            if (hv)   { nM.x = Ai[dof + hwm]; nM.y = Bi[dof + hwm]; }
            if (anyh) { nH.x = Ai[dof + hwh]; nH.y = Bi[dof + hwh]; }
        }
    }

    // W-blur results carried from phase A to phase B (5 registers)
    v2f wb_b = 0.f, wb_bs = 0.f;
    float wb_bij = 0.f;

    const int NIT = DCHUNK + 6;          // 26
    for (int k = 0; k < NIT; ++k) {
        const bool wval = (k >= 1) && (k <= DCHUNK + 4);

        // ================= Phase A: LDS reads =================
        // this iteration's mask value
        const int  dout = d0 - 6 + k;
        const bool outv = (k >= 6) && (r < TH);
        float mval = 0.f;
        if (outv) mval = Mi[dout * SD + mbase];

        // H-blur of wbA/wbC (W-blur results of slice staged at k-2) + D-pipeline
        if (k >= 2 && r < TH) {
            const v4f a0 = wbA[r][c];
            const v4f a1 = wbA[r + 1][c];
            const v4f a2 = wbA[r + 2][c];
            const v4f a3 = wbA[r + 3][c];
            const v4f a4 = wbA[r + 4][c];
            const float c0 = wbC[r][c];
            const float c1 = wbC[r + 1][c];
            const float c2 = wbC[r + 2][c];
            const float c3 = wbC[r + 3][c];
            const float c4 = wbC[r + 4][c];
            const v2f h1 = K0*(a0.xy+a4.xy) + K1*(a1.xy+a3.xy) + K2*a2.xy; // (hI,hJ)
            const v2f h2 = K0*(a0.zw+a4.zw) + K1*(a1.zw+a3.zw) + K2*a2.zw; // (hII,hJJ)
            const float hc = K0*(c0+c4) + K1*(c1+c3) + K2*c2;

            if (outv) {
                const v2f bP = K0*(pP0+h1) + K1*(pP1+pP3) + K2*pP2;   // (bI,bJ)
                const v2f bS = K0*(pQ0+h2) + K1*(pQ1+pQ3) + K2*pQ2;   // (bII,bJJ)
                const float bC = K0*(pC0+hc) + K1*(pC1+pC3) + K2*pC2; // bIJ
                const float cross = bC - bP.x * bP.y;
                const float vI = fmaxf(bS.x - bP.x * bP.x, 0.f) + 1e-5f;
                const float vJ = fmaxf(bS.y - bP.y * bP.y, 0.f) + 1e-5f;
                const float lncc = 1.0f - cross * rsqrtf(vI * vJ);
                accL += lncc * mval;
                accM += mval;
            }

            pP0 = pP1; pP1 = pP2; pP2 = pP3; pP3 = h1;
            pQ0 = pQ1; pQ1 = pQ2; pQ2 = pQ3; pQ3 = h2;
            pC0 = pC1; pC1 = pC2; pC2 = pC3; pC3 = hc;
        }

        // W-blur of the slice staged last iteration: read sIJ, compute into regs
        if (wval) {
            const v2f v0 = sIJ[r][c];
            const v2f v1 = sIJ[r][c + 1];
            const v2f v2 = sIJ[r][c + 2];
            const v2f v3 = sIJ[r][c + 3];
            const v2f v4 = sIJ[r][c + 4];
            wb_b   = K0*(v0+v4) + K1*(v1+v3) + K2*v2;                     // (bI,bJ)
            wb_bs  = K0*(v0*v0+v4*v4) + K1*(v1*v1+v3*v3) + K2*(v2*v2);    // (bII,bJJ)
            wb_bij = K0*(v0.x*v0.y+v4.x*v4.y) + K1*(v1.x*v1.y+v3.x*v3.y) + K2*(v2.x*v2.y);
        }

        __syncthreads();

        // ================= Phase B: LDS writes =================
        if (wval) {
            wbA[r][c] = (v4f){wb_b.x, wb_b.y, wb_bs.x, wb_bs.y};
            wbC[r][c] = wb_bij;
        }
        if (k < DCHUNK + 4) {
            sIJ[r][c + 2] = nM;
            if (c < 2)        sIJ[r][c]     = nH;
            else if (c >= 30) sIJ[r][c + 4] = nH;
        }

        // prefetch slice k+1 (global, no LDS — latency hides into next Phase A)
        nM = 0.f; nH = 0.f;
        {
            const int dd = d0 - 1 + k;
            if ((k + 1 < DCHUNK + 4) && (dd >= 0) && (dd < DD)) {
                const int dof = dd * SD;
                if (hv)   { nM.x = Ai[dof + hwm]; nM.y = Bi[dof + hwm]; }
                if (anyh) { nH.x = Ai[dof + hwh]; nH.y = Bi[dof + hwh]; }
            }
        }

        __syncthreads();
    }

    // ---- reduction ----
#pragma unroll
    for (int off = 32; off > 0; off >>= 1) {
        accL += __shfl_down(accL, off, 64);
        accM += __shfl_down(accM, off, 64);
    }
    const int wave = tid >> 6;
    if ((tid & 63) == 0) { redL[wave] = accL; redM[wave] = accM; }
    __syncthreads();
    if (tid == 0) {
        float sL = 0.f, sM = 0.f;
#pragma unroll
        for (int kk = 0; kk < 10; ++kk) { sL += redL[kk]; sM += redM[kk]; }
        atomicAdd(&acc[0], (double)sL);
        atomicAdd(&acc[1], (double)sM);
    }
}

__global__ void lncc_final(const double* __restrict__ acc, float* __restrict__ out)
{
    out[0] = (float)(acc[0] / (acc[1] + 1e-8));
}

extern "C" void kernel_launch(void* const* d_in, const int* in_sizes, int n_in,
                              void* d_out, int out_size, void* d_ws, size_t ws_size,
                              hipStream_t stream)
{
    const float* A = (const float*)d_in[0];
    const float* B = (const float*)d_in[1];
    const float* M = (const float*)d_in[2];
    double* acc = (double*)d_ws;

    hipMemsetAsync(d_ws, 0, 2 * sizeof(double), stream);

    dim3 grid(WW / TW, HH / TH, NB * NCHUNK);   // (7, 12, 16) = 1344 blocks
    dim3 block(640);
    hipLaunchKernelGGL(lncc_main, grid, block, 0, stream, A, B, M, acc);
    hipLaunchKernelGGL(lncc_final, dim3(1), dim3(1), 0, stream, acc, (float*)d_out);
}